// Round 1
// baseline (653.809 us; speedup 1.0000x reference)
//
#include <hip/hip_runtime.h>
#include <cstdint>

// PQ ADC search, MI355X round 1 (exact baseline).
// B=32 queries, M=64 subspaces, KSUB=256, DSUB=4, N=1e6, k=64.
// Pipeline: table build -> sampled threshold -> exact scan+collect -> bitonic top-k.

#define BQ 32
#define MSUB 64
#define KSUB 256
#define DSUB 4
#define KOUT 64
#define NSAMP 16384
#define TAU_RANK 24        // tau = 24th smallest sampled distance
#define CAP 16384          // candidate storage per query
#define NSORT 4096         // bitonic sort size (>= candidate count w.h.p.)

// ---------------- K1: distance table, layout table[m][c][b] (2 MB) ----------------
__global__ __launch_bounds__(256) void build_table(const float* __restrict__ q,
                                                   const float* __restrict__ cw,
                                                   float* __restrict__ table) {
    int tid = blockIdx.x * 256 + threadIdx.x;      // 64*256*32 = 524288
    int b = tid & 31;
    int c = (tid >> 5) & 255;
    int m = tid >> 13;
    const float* qp = q + b * (MSUB * DSUB) + m * DSUB;
    const float* cp = cw + (m * KSUB + c) * DSUB;
    float s = 0.f;
#pragma unroll
    for (int d = 0; d < DSUB; ++d) { float t = qp[d] - cp[d]; s += t * t; }
    table[tid] = s;
}

// ---------------- K2a: distances for sampled n ----------------
__global__ __launch_bounds__(256) void sample_dists(const float* __restrict__ table,
                                                    const int* __restrict__ codes,
                                                    float* __restrict__ samp,
                                                    int stride, int offset) {
    int j = blockIdx.x * 256 + threadIdx.x;        // NSAMP threads
    int n = j * stride + offset;
    const int* crow = codes + (long)n * MSUB;
    float acc[BQ];
#pragma unroll
    for (int b = 0; b < BQ; ++b) acc[b] = 0.f;
    for (int m = 0; m < MSUB; ++m) {
        int c = crow[m];
        const float* t = table + (m * KSUB + c) * BQ;
#pragma unroll
        for (int b = 0; b < BQ; ++b) acc[b] += t[b];
    }
#pragma unroll
    for (int b = 0; b < BQ; ++b) samp[b * NSAMP + j] = acc[b];
}

// ---------------- K2b: per-query threshold via bit-wise binary search ----------------
__global__ __launch_bounds__(256) void find_tau(const float* __restrict__ samp,
                                                float* __restrict__ tau) {
    __shared__ uint32_t sbits[NSAMP];              // 64 KB
    __shared__ int scount;
    int b = blockIdx.x;
    for (int i = threadIdx.x; i < NSAMP; i += 256)
        sbits[i] = __float_as_uint(samp[b * NSAMP + i]);   // positive floats: bits monotone
    __syncthreads();
    uint32_t lo = 0u, hi = 0x7F800000u;            // count(<=lo) < RANK <= count(<=hi)
    for (int it = 0; it < 31; ++it) {
        uint32_t mid = (lo + hi) >> 1;
        if (threadIdx.x == 0) scount = 0;
        __syncthreads();
        int c = 0;
        for (int i = threadIdx.x; i < NSAMP; i += 256) c += (sbits[i] <= mid) ? 1 : 0;
        atomicAdd(&scount, c);
        __syncthreads();
        int cnt = scount;
        __syncthreads();                            // protect scount reset next iter
        if (cnt >= TAU_RANK) hi = mid; else lo = mid;
    }
    if (threadIdx.x == 0) tau[b] = __uint_as_float(hi);
}

// ---------------- K3: exact scan + candidate collection ----------------
// 8 lanes per code row n; lane q4 accumulates queries 4*q4 .. 4*q4+3 as float4.
// Accumulation over m is sequential ascending -> matches reference summation order.
__global__ __launch_bounds__(256) void scan_collect(const float* __restrict__ table,
                                                    const int* __restrict__ codes,
                                                    const float* __restrict__ tau,
                                                    int* __restrict__ cnt,
                                                    int* __restrict__ cidx,
                                                    float* __restrict__ cdist,
                                                    int N) {
    int tid = blockIdx.x * 256 + threadIdx.x;
    int n = tid >> 3;
    if (n >= N) return;
    int q4 = tid & 7;
    const int* crow = codes + (long)n * MSUB;
    const float4* t4 = (const float4*)table;
    float4 acc = {0.f, 0.f, 0.f, 0.f};
#pragma unroll 8
    for (int m = 0; m < MSUB; ++m) {
        int c = crow[m];
        float4 v = t4[(m * KSUB + c) * 8 + q4];
        acc.x += v.x; acc.y += v.y; acc.z += v.z; acc.w += v.w;
    }
    float d[4] = {acc.x, acc.y, acc.z, acc.w};
    int b0 = q4 * 4;
#pragma unroll
    for (int j = 0; j < 4; ++j) {
        int b = b0 + j;
        if (d[j] <= tau[b]) {
            int pos = atomicAdd(&cnt[b], 1);
            if (pos < CAP) { cidx[b * CAP + pos] = n; cdist[b * CAP + pos] = d[j]; }
        }
    }
}

// ---------------- K4: per-query exact top-k via bitonic sort of (dist,idx) keys ----------------
__global__ __launch_bounds__(256) void final_topk(const int* __restrict__ cnt,
                                                  const int* __restrict__ cidx,
                                                  const float* __restrict__ cdist,
                                                  float* __restrict__ out) {
    __shared__ unsigned long long keys[NSORT];     // 32 KB
    int b = blockIdx.x;
    int m = cnt[b];
    if (m > NSORT) m = NSORT;
    for (int i = threadIdx.x; i < NSORT; i += 256) {
        unsigned long long k;
        if (i < m)
            k = ((unsigned long long)__float_as_uint(cdist[b * CAP + i]) << 32) |
                (unsigned int)cidx[b * CAP + i];
        else
            k = ~0ULL;
        keys[i] = k;
    }
    __syncthreads();
    for (int kk = 2; kk <= NSORT; kk <<= 1) {
        for (int j = kk >> 1; j > 0; j >>= 1) {
            for (int i = threadIdx.x; i < NSORT; i += 256) {
                int ixj = i ^ j;
                if (ixj > i) {
                    unsigned long long a = keys[i], c = keys[ixj];
                    bool up = ((i & kk) == 0);
                    if ((a > c) == up) { keys[i] = c; keys[ixj] = a; }
                }
            }
            __syncthreads();
        }
    }
    // ascending: rank r = keys[r]; write dists then indices (as float32)
    for (int r = threadIdx.x; r < KOUT; r += 256) {
        unsigned long long k = keys[r];
        out[b * KOUT + r] = __uint_as_float((unsigned int)(k >> 32));
        out[BQ * KOUT + b * KOUT + r] = (float)(unsigned int)(k & 0xFFFFFFFFu);
    }
}

extern "C" void kernel_launch(void* const* d_in, const int* in_sizes, int n_in,
                              void* d_out, int out_size, void* d_ws, size_t ws_size,
                              hipStream_t stream) {
    const float* querys    = (const float*)d_in[0];
    const float* codewords = (const float*)d_in[1];
    const int*   codes     = (const int*)d_in[2];
    // d_in[3] is k (device scalar); k is fixed to 64 = out_size / (2*BQ).
    float* out = (float*)d_out;
    int N = in_sizes[2] / MSUB;                    // 1,000,000

    char* ws = (char*)d_ws;
    float* table = (float*)(ws);                           // 2 MB
    float* samp  = (float*)(ws + (2u << 20));              // 2 MB
    float* tau   = (float*)(ws + (4u << 20));              // 128 B
    int*   cnt   = (int*)  (ws + (4u << 20) + 4096);       // 128 B
    int*   cidx  = (int*)  (ws + (4u << 20) + 8192);       // 2 MB
    float* cdist = (float*)(ws + (6u << 20) + 8192);       // 2 MB

    hipMemsetAsync(cnt, 0, BQ * sizeof(int), stream);

    build_table<<<(MSUB * KSUB * BQ) / 256, 256, 0, stream>>>(querys, codewords, table);

    int stride = N / NSAMP;                        // 61
    int offset = 17;                               // max n = 16383*61+17 < N
    sample_dists<<<NSAMP / 256, 256, 0, stream>>>(table, codes, samp, stride, offset);

    find_tau<<<BQ, 256, 0, stream>>>(samp, tau);

    long total = (long)N * 8;
    int blocks = (int)((total + 255) / 256);
    scan_collect<<<blocks, 256, 0, stream>>>(table, codes, tau, cnt, cidx, cdist, N);

    final_topk<<<BQ, 256, 0, stream>>>(cnt, cidx, cdist, out);
}